// Round 1
// baseline (1876.722 us; speedup 1.0000x reference)
//
#include <hip/hip_runtime.h>

// Problem constants (match reference)
#define NN 50000      // nodes
#define PM 4          // metapaths
#define EE 500000     // edges per metapath
#define INF_ 128      // in feats
#define NH 8          // heads
#define FF 32         // feats/head
#define HF 256        // NH*FF
#define HS 128        // semantic hidden
#define BG 128        // graphs
#define OUTC 2

// ---------------------------------------------------------------------------
// GEMM1: hp = h[M,128] @ W[128,256], fp32, 128x128 tile, 8x8/thread
// ---------------------------------------------------------------------------
__global__ __launch_bounds__(256) void gemm1_kernel(
    const float* __restrict__ A, const float* __restrict__ Bw,
    float* __restrict__ C, int M) {
  __shared__ float As[16][128];
  __shared__ float Bs[16][128];
  int tid = threadIdx.x;
  int tx = tid & 15, ty = tid >> 4;
  int row0 = blockIdx.x * 128;
  int col0 = blockIdx.y * 128;
  float acc[8][8] = {};
  for (int kc = 0; kc < 128; kc += 16) {
    #pragma unroll
    for (int i = 0; i < 2; i++) {
      int f4 = tid * 2 + i;
      int r = f4 >> 2, kq = f4 & 3;
      int grow = row0 + r;
      float4 v = make_float4(0.f, 0.f, 0.f, 0.f);
      if (grow < M) v = *(const float4*)(A + (size_t)grow * 128 + kc + kq * 4);
      As[kq * 4 + 0][r] = v.x; As[kq * 4 + 1][r] = v.y;
      As[kq * 4 + 2][r] = v.z; As[kq * 4 + 3][r] = v.w;
    }
    #pragma unroll
    for (int i = 0; i < 2; i++) {
      int f4 = tid * 2 + i;
      int k = f4 >> 5, cq = f4 & 31;
      *(float4*)&Bs[k][cq * 4] = *(const float4*)(Bw + (size_t)(kc + k) * 256 + col0 + cq * 4);
    }
    __syncthreads();
    #pragma unroll
    for (int kk = 0; kk < 16; kk++) {
      float4 a0 = *(const float4*)&As[kk][ty * 8];
      float4 a1 = *(const float4*)&As[kk][ty * 8 + 4];
      float4 b0 = *(const float4*)&Bs[kk][tx * 8];
      float4 b1 = *(const float4*)&Bs[kk][tx * 8 + 4];
      float av[8] = {a0.x, a0.y, a0.z, a0.w, a1.x, a1.y, a1.z, a1.w};
      float bv[8] = {b0.x, b0.y, b0.z, b0.w, b1.x, b1.y, b1.z, b1.w};
      #pragma unroll
      for (int i2 = 0; i2 < 8; i2++)
        #pragma unroll
        for (int j2 = 0; j2 < 8; j2++)
          acc[i2][j2] += av[i2] * bv[j2];
    }
    __syncthreads();
  }
  #pragma unroll
  for (int i = 0; i < 8; i++) {
    int grow = row0 + ty * 8 + i;
    if (grow < M) {
      #pragma unroll
      for (int j = 0; j < 8; j += 4) {
        *(float4*)(C + (size_t)grow * 256 + col0 + tx * 8 + j) =
            make_float4(acc[i][j], acc[i][j + 1], acc[i][j + 2], acc[i][j + 3]);
      }
    }
  }
}

// ---------------------------------------------------------------------------
// GEMM2 + semantic epilogue: w_n = tanh(emb@W1 + b1) . W2 ; atomicAdd sum(w)
// emb[M,256] @ W1[256,128]; no C materialization.
// ---------------------------------------------------------------------------
__global__ __launch_bounds__(256) void gemm2_kernel(
    const float* __restrict__ A, const float* __restrict__ Bw,
    const float* __restrict__ bias1, const float* __restrict__ W2,
    float* __restrict__ wsum, int M) {
  __shared__ float As[16][128];
  __shared__ float Bs[16][128];
  __shared__ float red[128][17];
  __shared__ float rsum[128];
  int tid = threadIdx.x;
  int tx = tid & 15, ty = tid >> 4;
  int row0 = blockIdx.x * 128;
  float acc[8][8] = {};
  for (int kc = 0; kc < 256; kc += 16) {
    #pragma unroll
    for (int i = 0; i < 2; i++) {
      int f4 = tid * 2 + i;
      int r = f4 >> 2, kq = f4 & 3;
      int grow = row0 + r;
      float4 v = make_float4(0.f, 0.f, 0.f, 0.f);
      if (grow < M) v = *(const float4*)(A + (size_t)grow * 256 + kc + kq * 4);
      As[kq * 4 + 0][r] = v.x; As[kq * 4 + 1][r] = v.y;
      As[kq * 4 + 2][r] = v.z; As[kq * 4 + 3][r] = v.w;
    }
    #pragma unroll
    for (int i = 0; i < 2; i++) {
      int f4 = tid * 2 + i;
      int k = f4 >> 5, cq = f4 & 31;
      *(float4*)&Bs[k][cq * 4] = *(const float4*)(Bw + (size_t)(kc + k) * 128 + cq * 4);
    }
    __syncthreads();
    #pragma unroll
    for (int kk = 0; kk < 16; kk++) {
      float4 a0 = *(const float4*)&As[kk][ty * 8];
      float4 a1 = *(const float4*)&As[kk][ty * 8 + 4];
      float4 b0 = *(const float4*)&Bs[kk][tx * 8];
      float4 b1 = *(const float4*)&Bs[kk][tx * 8 + 4];
      float av[8] = {a0.x, a0.y, a0.z, a0.w, a1.x, a1.y, a1.z, a1.w};
      float bv[8] = {b0.x, b0.y, b0.z, b0.w, b1.x, b1.y, b1.z, b1.w};
      #pragma unroll
      for (int i2 = 0; i2 < 8; i2++)
        #pragma unroll
        for (int j2 = 0; j2 < 8; j2++)
          acc[i2][j2] += av[i2] * bv[j2];
    }
    __syncthreads();
  }
  // epilogue: per-row partial of tanh(c + b1[col]) * W2[col]
  float pw[8];
  #pragma unroll
  for (int i = 0; i < 8; i++) {
    float s = 0.f;
    #pragma unroll
    for (int j = 0; j < 8; j++) {
      int col = tx * 8 + j;
      s += tanhf(acc[i][j] + bias1[col]) * W2[col];
    }
    pw[i] = s;
  }
  #pragma unroll
  for (int i = 0; i < 8; i++) {
    int r = ty * 8 + i;
    red[r][tx] = (row0 + r < M) ? pw[i] : 0.f;
  }
  __syncthreads();
  if (tid < 128) {
    float w = 0.f;
    #pragma unroll
    for (int t = 0; t < 16; t++) w += red[tid][t];
    rsum[tid] = w;
  }
  __syncthreads();
  for (int s = 64; s > 0; s >>= 1) {
    if (tid < s) rsum[tid] += rsum[tid + s];
    __syncthreads();
  }
  if (tid == 0) atomicAdd(wsum, rsum[0]);
}

// ---------------------------------------------------------------------------
// el/er: per (node, head) dot of hp row-slice with attn vectors
// ---------------------------------------------------------------------------
__global__ __launch_bounds__(256) void elr_kernel(
    const float* __restrict__ hp, const float* __restrict__ al,
    const float* __restrict__ ar, float* __restrict__ el,
    float* __restrict__ er, int N) {
  int t = blockIdx.x * 256 + threadIdx.x;
  if (t >= N * NH) return;
  int n = t >> 3, h = t & 7;
  const float* hr = hp + (size_t)n * HF + h * FF;
  const float* alp = al + h * FF;
  const float* arp = ar + h * FF;
  float sl = 0.f, sr = 0.f;
  #pragma unroll
  for (int j = 0; j < 8; j++) {
    float4 hv = *(const float4*)(hr + j * 4);
    float4 av = *(const float4*)(alp + j * 4);
    float4 rv = *(const float4*)(arp + j * 4);
    sl += hv.x * av.x + hv.y * av.y + hv.z * av.z + hv.w * av.w;
    sr += hv.x * rv.x + hv.y * rv.y + hv.z * rv.z + hv.w * rv.w;
  }
  el[t] = sl;
  er[t] = sr;
}

// ---------------------------------------------------------------------------
// CSR build
// ---------------------------------------------------------------------------
__global__ void count_kernel(const int* __restrict__ dst, int* __restrict__ deg, int PE, int E) {
  int t = blockIdx.x * 256 + threadIdx.x;
  if (t >= PE) return;
  int p = t / E;
  atomicAdd(&deg[p * NN + dst[t]], 1);
}

__global__ void cntg_kernel(const int* __restrict__ gid, float* __restrict__ cnt, int N) {
  int t = blockIdx.x * 256 + threadIdx.x;
  if (t < N) atomicAdd(&cnt[gid[t]], 1.0f);
}

__global__ __launch_bounds__(1024) void scan_kernel(
    const int* __restrict__ deg, int* __restrict__ off, int N) {
  int p = blockIdx.x;
  const int* d = deg + (size_t)p * N;
  int* o = off + (size_t)p * (N + 1);
  __shared__ int sm[1024];
  __shared__ int carry_s;
  if (threadIdx.x == 0) carry_s = 0;
  __syncthreads();
  for (int base = 0; base < N; base += 1024) {
    int i = base + (int)threadIdx.x;
    int v = (i < N) ? d[i] : 0;
    sm[threadIdx.x] = v;
    __syncthreads();
    for (int ofs = 1; ofs < 1024; ofs <<= 1) {
      int t = (threadIdx.x >= (unsigned)ofs) ? sm[threadIdx.x - ofs] : 0;
      __syncthreads();
      sm[threadIdx.x] += t;
      __syncthreads();
    }
    int carry = carry_s;
    if (i < N) o[i] = carry + sm[threadIdx.x] - v;   // exclusive
    __syncthreads();
    if (threadIdx.x == 0) carry_s = carry + sm[1023];
    __syncthreads();
  }
  if (threadIdx.x == 0) o[N] = carry_s;
}

__global__ void fill_kernel(const int* __restrict__ src, const int* __restrict__ dst,
                            const int* __restrict__ off, int* __restrict__ cur,
                            int* __restrict__ csr, int PE, int E) {
  int t = blockIdx.x * 256 + threadIdx.x;
  if (t >= PE) return;
  int p = t / E;
  int d = dst[t];
  int slot = off[(size_t)p * (NN + 1) + d] + atomicAdd(&cur[p * NN + d], 1);
  csr[(size_t)p * E + slot] = src[t];
}

// ---------------------------------------------------------------------------
// Aggregation: one wave per dst node. den in-register, then alpha-weighted
// gather of hp[src], + bias, ELU -> emb
// ---------------------------------------------------------------------------
__global__ __launch_bounds__(256) void agg_kernel(
    const float* __restrict__ hp, const float* __restrict__ el,
    const float* __restrict__ er, const int* __restrict__ csr,
    const int* __restrict__ off, const float* __restrict__ bias,
    float* __restrict__ emb, int N) {
  int n = blockIdx.x * 4 + (threadIdx.x >> 6);
  if (n >= N) return;
  int lane = threadIdx.x & 63;
  int h = lane >> 3;                 // head for the 4 cols this lane owns
  int e0 = off[n], e1 = off[n + 1];
  float erh = er[n * NH + h];
  float den = 0.f;
  for (int e = e0; e < e1; e++) {
    int s = csr[e];
    float x = el[s * NH + h] + erh;
    x = (x > 0.f) ? x : 0.2f * x;
    den += expf(x);
  }
  float ax = 0.f, ay = 0.f, az = 0.f, aw = 0.f;
  for (int e = e0; e < e1; e++) {
    int s = csr[e];
    float x = el[s * NH + h] + erh;
    x = (x > 0.f) ? x : 0.2f * x;
    float alpha = expf(x) / den;
    float4 v = *(const float4*)(hp + (size_t)s * HF + lane * 4);
    ax += alpha * v.x; ay += alpha * v.y; az += alpha * v.z; aw += alpha * v.w;
  }
  float4 bv = *(const float4*)(bias + lane * 4);
  float ox = ax + bv.x, oy = ay + bv.y, oz = az + bv.z, ow = aw + bv.w;
  ox = (ox > 0.f) ? ox : expf(ox) - 1.f;
  oy = (oy > 0.f) ? oy : expf(oy) - 1.f;
  oz = (oz > 0.f) ? oz : expf(oz) - 1.f;
  ow = (ow > 0.f) ? ow : expf(ow) - 1.f;
  *(float4*)(emb + (size_t)n * HF + lane * 4) = make_float4(ox, oy, oz, ow);
}

// ---------------------------------------------------------------------------
// Pooling: LDS 2-stage segment sum of emb by graph id (64-feat slice/block)
// ---------------------------------------------------------------------------
__global__ __launch_bounds__(256) void pool_kernel(
    const float* __restrict__ emb, const int* __restrict__ gid,
    float* __restrict__ pool, int N) {
  __shared__ float acc[BG * 64];
  int f0 = blockIdx.x * 64;
  int lane = threadIdx.x & 63, grp = threadIdx.x >> 6;
  for (int i = threadIdx.x; i < BG * 64; i += 256) acc[i] = 0.f;
  __syncthreads();
  int nb = (int)gridDim.y;
  int chunk = (N + nb - 1) / nb;
  int start = blockIdx.y * chunk;
  int end = min(start + chunk, N);
  int glen = (end - start + 3) >> 2;
  int gstart = start + grp * glen;
  int gend = min(gstart + glen, end);
  for (int n = gstart; n < gend; n += 4) {
    int m = min(4, gend - n);
    float v[4]; int g[4];
    #pragma unroll
    for (int j = 0; j < 4; j++) {
      if (j < m) {
        g[j] = gid[n + j];
        v[j] = emb[(size_t)(n + j) * HF + f0 + lane];
      }
    }
    #pragma unroll
    for (int j = 0; j < 4; j++)
      if (j < m) atomicAdd(&acc[g[j] * 64 + lane], v[j]);
  }
  __syncthreads();
  for (int i = threadIdx.x; i < BG * 64; i += 256) {
    float v = acc[i];
    if (v != 0.f) {
      int g = i >> 6, f = i & 63;
      atomicAdd(&pool[g * HF + f0 + f], v);
    }
  }
}

// ---------------------------------------------------------------------------
// Final: beta softmax, pooled = sum_p beta_p pool_p / cnt, logits
// ---------------------------------------------------------------------------
__global__ __launch_bounds__(256) void final_kernel(
    const float* __restrict__ pool, const float* __restrict__ wsum,
    const float* __restrict__ cnt, const float* __restrict__ clsW,
    const float* __restrict__ clsb, float* __restrict__ out, int N) {
  int b = blockIdx.x;
  int f = threadIdx.x;
  float wm[PM];
  float mx = -1e30f;
  #pragma unroll
  for (int p = 0; p < PM; p++) { wm[p] = wsum[p] / (float)N; mx = fmaxf(mx, wm[p]); }
  float es = 0.f, e[PM];
  #pragma unroll
  for (int p = 0; p < PM; p++) { e[p] = expf(wm[p] - mx); es += e[p]; }
  float c = fmaxf(cnt[b], 1.f);
  float v = 0.f;
  #pragma unroll
  for (int p = 0; p < PM; p++)
    v += (e[p] / es) * pool[((size_t)p * BG + b) * HF + f];
  v /= c;
  out[256 + (size_t)b * HF + f] = v;   // pooled after 256 logits
  __shared__ float sm[256];
  sm[f] = v * clsW[f * 2 + 0];
  __syncthreads();
  for (int st = 128; st > 0; st >>= 1) {
    if (f < st) sm[f] += sm[f + st];
    __syncthreads();
  }
  float l0 = sm[0];
  __syncthreads();
  sm[f] = v * clsW[f * 2 + 1];
  __syncthreads();
  for (int st = 128; st > 0; st >>= 1) {
    if (f < st) sm[f] += sm[f + st];
    __syncthreads();
  }
  if (f == 0) {
    out[b * 2 + 0] = l0 + clsb[0];
    out[b * 2 + 1] = sm[0] + clsb[1];
  }
}

// ---------------------------------------------------------------------------
extern "C" void kernel_launch(void* const* d_in, const int* in_sizes, int n_in,
                              void* d_out, int out_size, void* d_ws, size_t ws_size,
                              hipStream_t stream) {
  const float* h       = (const float*)d_in[0];
  const float* Wg      = (const float*)d_in[1];
  const float* attn_l  = (const float*)d_in[2];
  const float* attn_r  = (const float*)d_in[3];
  const float* gatb    = (const float*)d_in[4];
  const float* semW1   = (const float*)d_in[5];
  const float* semb1   = (const float*)d_in[6];
  const float* semW2   = (const float*)d_in[7];
  const float* clsW    = (const float*)d_in[8];
  const float* clsb    = (const float*)d_in[9];
  const int*   src     = (const int*)d_in[10];
  const int*   dst     = (const int*)d_in[11];
  const int*   gid     = (const int*)d_in[12];
  float* out = (float*)d_out;

  // workspace layout
  char* ws = (char*)d_ws;
  size_t o = 0;
  auto alloc = [&](size_t bytes) { size_t r = o; o += (bytes + 255) & ~(size_t)255; return r; };
  float* hp   = (float*)(ws + alloc((size_t)NN * HF * 4));
  float* emb  = (float*)(ws + alloc((size_t)NN * HF * 4));
  float* el   = (float*)(ws + alloc((size_t)NN * NH * 4));
  float* er   = (float*)(ws + alloc((size_t)NN * NH * 4));
  int*   deg  = (int*)(ws + alloc((size_t)PM * NN * 4));
  int*   off  = (int*)(ws + alloc((size_t)PM * (NN + 1) * 4));
  int*   cur  = (int*)(ws + alloc((size_t)PM * NN * 4));
  int*   csr  = (int*)(ws + alloc((size_t)PM * EE * 4));
  float* pool = (float*)(ws + alloc((size_t)PM * BG * HF * 4));
  float* wsum = (float*)(ws + alloc(PM * 4));
  float* cnt  = (float*)(ws + alloc(BG * 4));

  hipMemsetAsync(deg, 0, (size_t)PM * NN * 4, stream);
  hipMemsetAsync(cur, 0, (size_t)PM * NN * 4, stream);
  hipMemsetAsync(pool, 0, (size_t)PM * BG * HF * 4, stream);
  hipMemsetAsync(wsum, 0, PM * 4, stream);
  hipMemsetAsync(cnt, 0, BG * 4, stream);

  const int PE = PM * EE;
  count_kernel<<<(PE + 255) / 256, 256, 0, stream>>>(dst, deg, PE, EE);
  cntg_kernel<<<(NN + 255) / 256, 256, 0, stream>>>(gid, cnt, NN);
  scan_kernel<<<PM, 1024, 0, stream>>>(deg, off, NN);
  fill_kernel<<<(PE + 255) / 256, 256, 0, stream>>>(src, dst, off, cur, csr, PE, EE);

  for (int p = 0; p < PM; p++) {
    gemm1_kernel<<<dim3((NN + 127) / 128, 2), 256, 0, stream>>>(
        h, Wg + (size_t)p * INF_ * HF, hp, NN);
    elr_kernel<<<(NN * NH + 255) / 256, 256, 0, stream>>>(
        hp, attn_l + (size_t)p * HF, attn_r + (size_t)p * HF, el, er, NN);
    agg_kernel<<<(NN + 3) / 4, 256, 0, stream>>>(
        hp, el, er, csr + (size_t)p * EE, off + (size_t)p * (NN + 1),
        gatb + (size_t)p * HF, emb, NN);
    gemm2_kernel<<<(NN + 127) / 128, 256, 0, stream>>>(
        emb, semW1, semb1, semW2, wsum + p, NN);
    pool_kernel<<<dim3(4, 64), 256, 0, stream>>>(
        emb, gid, pool + (size_t)p * BG * HF, NN);
  }

  final_kernel<<<BG, 256, 0, stream>>>(pool, wsum, cnt, clsW, clsb, out, NN);
}

// Round 2
// 1265.111 us; speedup vs baseline: 1.4834x; 1.4834x over previous
//
#include <hip/hip_runtime.h>

#define NN 50000
#define PM 4
#define EE 500000
#define INF_ 128
#define NH 8
#define FF 32
#define HF 256
#define HS 128
#define BG 128
#define OUTC 2

typedef __attribute__((ext_vector_type(8))) short bf16x8;
typedef __attribute__((ext_vector_type(4))) float f32x4;

__device__ __forceinline__ float b2f(unsigned short x) {
  unsigned u = ((unsigned)x) << 16;
  return __builtin_bit_cast(float, u);
}
__device__ __forceinline__ unsigned short f2b(float f) {
  unsigned u = __builtin_bit_cast(unsigned, f);
  u += 0x7fff + ((u >> 16) & 1);   // RNE
  return (unsigned short)(u >> 16);
}

// ---------------------------------------------------------------------------
// fp32 -> bf16 (contiguous, float4 granular)
__global__ void f2b_kernel(const float* __restrict__ src, unsigned short* __restrict__ dst, int n4) {
  int t = blockIdx.x * 256 + threadIdx.x;
  if (t >= n4) return;
  float4 v = *(const float4*)(src + (size_t)t * 4);
  ushort4 o;
  o.x = f2b(v.x); o.y = f2b(v.y); o.z = f2b(v.z); o.w = f2b(v.w);
  *(ushort4*)(dst + (size_t)t * 4) = o;
}

// Wg [P][128 k][256 n] -> Wb_t [P][256 n][128 k] bf16
__global__ void twg_kernel(const float* __restrict__ Wg, unsigned short* __restrict__ Wt) {
  int t = blockIdx.x * 256 + threadIdx.x;   // 4*256*128
  if (t >= PM * HF * INF_) return;
  int p = t >> 15, rem = t & 32767;
  int n = rem >> 7, k = rem & 127;
  Wt[(size_t)p * 32768 + n * 128 + k] = f2b(Wg[(size_t)p * 32768 + k * 256 + n]);
}

// semW1 [256 k][128 n] -> W1_t [128 n][256 k] bf16
__global__ void tw1_kernel(const float* __restrict__ W1, unsigned short* __restrict__ Wt) {
  int t = blockIdx.x * 256 + threadIdx.x;   // 32768
  if (t >= HF * HS) return;
  int n = t >> 8, k = t & 255;
  Wt[n * 256 + k] = f2b(W1[k * 128 + n]);
}

// fold attn into per-k weights: wl[p][k][h] = sum_f Wg[p][k][h*32+f]*al[p][h*32+f]
__global__ void fold_kernel(const float* __restrict__ Wg, const float* __restrict__ al,
                            const float* __restrict__ ar, float* __restrict__ wl,
                            float* __restrict__ wr) {
  int t = blockIdx.x * 256 + threadIdx.x;   // 4*128*8 = 4096
  if (t >= PM * INF_ * NH) return;
  int p = t >> 10, rem = t & 1023;
  int k = rem >> 3, h = rem & 7;
  const float* wrow = Wg + (size_t)p * 32768 + k * 256 + h * 32;
  const float* alp = al + p * 256 + h * 32;
  const float* arp = ar + p * 256 + h * 32;
  float sl = 0.f, sr = 0.f;
  #pragma unroll
  for (int f = 0; f < 32; f++) { sl += wrow[f] * alp[f]; sr += wrow[f] * arp[f]; }
  wl[t] = sl; wr[t] = sr;
}

// el/er = h @ wl / h @ wr  (fp32 exact)
__global__ __launch_bounds__(256) void elr_kernel(
    const float* __restrict__ h, const float* __restrict__ wl,
    const float* __restrict__ wr, float* __restrict__ el, float* __restrict__ er, int N) {
  __shared__ float wls[128 * 8], wrs[128 * 8];
  for (int i = threadIdx.x; i < 1024; i += 256) { wls[i] = wl[i]; wrs[i] = wr[i]; }
  __syncthreads();
  int n = blockIdx.x * 256 + threadIdx.x;
  if (n >= N) return;
  float accl[8] = {}, accr[8] = {};
  for (int k4 = 0; k4 < 32; k4++) {
    float4 hv = *(const float4*)(h + (size_t)n * 128 + k4 * 4);
    float vv[4] = {hv.x, hv.y, hv.z, hv.w};
    #pragma unroll
    for (int j = 0; j < 4; j++) {
      float v = vv[j];
      int k = k4 * 4 + j;
      #pragma unroll
      for (int hh = 0; hh < 8; hh++) {
        accl[hh] += v * wls[k * 8 + hh];
        accr[hh] += v * wrs[k * 8 + hh];
      }
    }
  }
  *(float4*)(el + (size_t)n * 8)     = make_float4(accl[0], accl[1], accl[2], accl[3]);
  *(float4*)(el + (size_t)n * 8 + 4) = make_float4(accl[4], accl[5], accl[6], accl[7]);
  *(float4*)(er + (size_t)n * 8)     = make_float4(accr[0], accr[1], accr[2], accr[3]);
  *(float4*)(er + (size_t)n * 8 + 4) = make_float4(accr[4], accr[5], accr[6], accr[7]);
}

// ---------------------------------------------------------------------------
// GEMM1: hp_b[M,256] = h_b[M,128] @ W (Wt is [256 n][128 k] bf16). BM=64, BN=128.
__global__ __launch_bounds__(256) void gemm1_kernel(
    const unsigned short* __restrict__ hA, const unsigned short* __restrict__ Bt,
    unsigned short* __restrict__ Cb, int M) {
  __shared__ unsigned short As[64 * 128];
  __shared__ unsigned short Bs[128 * 128];
  int tid = threadIdx.x;
  int row0 = blockIdx.x * 64, col0 = blockIdx.y * 128;
  // stage A: 64 rows x 16 groups of 8 bf16
  #pragma unroll
  for (int i = 0; i < 4; i++) {
    int c = i * 256 + tid;
    int row = c >> 4, g = c & 15;
    int grow = row0 + row;
    uint4 v = make_uint4(0, 0, 0, 0);
    if (grow < M) v = *(const uint4*)(hA + (size_t)grow * 128 + g * 8);
    *(uint4*)&As[row * 128 + ((g ^ (row & 15)) << 3)] = v;
  }
  // stage B: 128 n-rows x 16 groups
  #pragma unroll
  for (int i = 0; i < 8; i++) {
    int c = i * 256 + tid;
    int row = c >> 4, g = c & 15;
    uint4 v = *(const uint4*)(Bt + (size_t)(col0 + row) * 128 + g * 8);
    *(uint4*)&Bs[row * 128 + ((g ^ (row & 15)) << 3)] = v;
  }
  __syncthreads();
  int wave = tid >> 6, lane = tid & 63;
  int ln = lane & 15, quad = lane >> 4;
  int mbase = (wave >> 1) * 32, nbase = (wave & 1) * 64;
  f32x4 acc[2][4] = {};
  #pragma unroll
  for (int ks = 0; ks < 4; ks++) {
    int g = ks * 4 + quad;
    bf16x8 a[2], b[4];
    #pragma unroll
    for (int mi = 0; mi < 2; mi++) {
      int r = mbase + mi * 16 + ln;
      a[mi] = *(const bf16x8*)&As[r * 128 + ((g ^ ln) << 3)];
    }
    #pragma unroll
    for (int ni = 0; ni < 4; ni++) {
      int r = nbase + ni * 16 + ln;
      b[ni] = *(const bf16x8*)&Bs[r * 128 + ((g ^ ln) << 3)];
    }
    #pragma unroll
    for (int mi = 0; mi < 2; mi++)
      #pragma unroll
      for (int ni = 0; ni < 4; ni++)
        acc[mi][ni] = __builtin_amdgcn_mfma_f32_16x16x32_bf16(a[mi], b[ni], acc[mi][ni], 0, 0, 0);
  }
  #pragma unroll
  for (int mi = 0; mi < 2; mi++) {
    int gm0 = row0 + mbase + mi * 16 + quad * 4;
    #pragma unroll
    for (int ni = 0; ni < 4; ni++) {
      int gn = col0 + nbase + ni * 16 + ln;
      #pragma unroll
      for (int r = 0; r < 4; r++) {
        int gm = gm0 + r;
        if (gm < M) Cb[(size_t)gm * 256 + gn] = f2b(acc[mi][ni][r]);
      }
    }
  }
}

// ---------------------------------------------------------------------------
// GEMM2 + semantic epilogue: w = tanh(emb@W1+b1).W2 summed over all nodes.
// A = emb_b [M,256] bf16, Bt = W1_t [128 n][256 k] bf16. BM=64, BN=128, 2 k-chunks.
__global__ __launch_bounds__(256) void gemm2_kernel(
    const unsigned short* __restrict__ A, const unsigned short* __restrict__ Bt,
    const float* __restrict__ b1, const float* __restrict__ W2,
    float* __restrict__ wsum, int M) {
  __shared__ unsigned short As[64 * 128];
  __shared__ unsigned short Bs[128 * 128];
  int tid = threadIdx.x;
  int row0 = blockIdx.x * 64;
  int wave = tid >> 6, lane = tid & 63;
  int ln = lane & 15, quad = lane >> 4;
  int mbase = (wave >> 1) * 32, nbase = (wave & 1) * 64;
  f32x4 acc[2][4] = {};
  for (int kc = 0; kc < 2; kc++) {
    #pragma unroll
    for (int i = 0; i < 4; i++) {
      int c = i * 256 + tid;
      int row = c >> 4, g = c & 15;
      int grow = row0 + row;
      uint4 v = make_uint4(0, 0, 0, 0);
      if (grow < M) v = *(const uint4*)(A + (size_t)grow * 256 + kc * 128 + g * 8);
      *(uint4*)&As[row * 128 + ((g ^ (row & 15)) << 3)] = v;
    }
    #pragma unroll
    for (int i = 0; i < 8; i++) {
      int c = i * 256 + tid;
      int row = c >> 4, g = c & 15;
      uint4 v = *(const uint4*)(Bt + (size_t)row * 256 + kc * 128 + g * 8);
      *(uint4*)&Bs[row * 128 + ((g ^ (row & 15)) << 3)] = v;
    }
    __syncthreads();
    #pragma unroll
    for (int ks = 0; ks < 4; ks++) {
      int g = ks * 4 + quad;
      bf16x8 a[2], b[4];
      #pragma unroll
      for (int mi = 0; mi < 2; mi++) {
        int r = mbase + mi * 16 + ln;
        a[mi] = *(const bf16x8*)&As[r * 128 + ((g ^ ln) << 3)];
      }
      #pragma unroll
      for (int ni = 0; ni < 4; ni++) {
        int r = nbase + ni * 16 + ln;
        b[ni] = *(const bf16x8*)&Bs[r * 128 + ((g ^ ln) << 3)];
      }
      #pragma unroll
      for (int mi = 0; mi < 2; mi++)
        #pragma unroll
        for (int ni = 0; ni < 4; ni++)
          acc[mi][ni] = __builtin_amdgcn_mfma_f32_16x16x32_bf16(a[mi], b[ni], acc[mi][ni], 0, 0, 0);
    }
    __syncthreads();
  }
  // epilogue: sum tanh(c + b1[col]) * W2[col] over valid rows
  float b1v[4], w2v[4];
  #pragma unroll
  for (int ni = 0; ni < 4; ni++) {
    int col = nbase + ni * 16 + ln;
    b1v[ni] = b1[col]; w2v[ni] = W2[col];
  }
  float s = 0.f;
  #pragma unroll
  for (int mi = 0; mi < 2; mi++) {
    int gm0 = row0 + mbase + mi * 16 + quad * 4;
    #pragma unroll
    for (int r = 0; r < 4; r++) {
      if (gm0 + r < M) {
        #pragma unroll
        for (int ni = 0; ni < 4; ni++)
          s += tanhf(acc[mi][ni][r] + b1v[ni]) * w2v[ni];
      }
    }
  }
  #pragma unroll
  for (int o = 32; o > 0; o >>= 1) s += __shfl_down(s, o);
  if (lane == 0) atomicAdd(wsum, s);
}

// ---------------------------------------------------------------------------
// CSR build
__global__ void count_kernel(const int* __restrict__ dst, int* __restrict__ deg, int PE, int E) {
  int t = blockIdx.x * 256 + threadIdx.x;
  if (t >= PE) return;
  int p = t / E;
  atomicAdd(&deg[p * NN + dst[t]], 1);
}

__global__ void cntg_kernel(const int* __restrict__ gid, float* __restrict__ cnt, int N) {
  int t = blockIdx.x * 256 + threadIdx.x;
  if (t < N) atomicAdd(&cnt[gid[t]], 1.0f);
}

__global__ __launch_bounds__(1024) void scan1_kernel(
    const int* __restrict__ deg, int* __restrict__ off, int* __restrict__ bsum, int N) {
  int p = blockIdx.y, b = blockIdx.x;
  const int* d = deg + (size_t)p * N;
  int* o = off + (size_t)p * (N + 1);
  __shared__ int sm[1024];
  int i = b * 1024 + (int)threadIdx.x;
  int v = (i < N) ? d[i] : 0;
  sm[threadIdx.x] = v;
  __syncthreads();
  for (int ofs = 1; ofs < 1024; ofs <<= 1) {
    int t = (threadIdx.x >= (unsigned)ofs) ? sm[threadIdx.x - ofs] : 0;
    __syncthreads();
    sm[threadIdx.x] += t;
    __syncthreads();
  }
  if (i < N) o[i] = sm[threadIdx.x] - v;
  if (threadIdx.x == 1023) bsum[p * 64 + b] = sm[1023];
}

__global__ void scan2_kernel(const int* __restrict__ bsum, int* __restrict__ bsumoff,
                             int* __restrict__ off, int NB) {
  int p = blockIdx.x, t = threadIdx.x;   // 64 threads
  int v = (t < NB) ? bsum[p * 64 + t] : 0;
  int orig = v;
  #pragma unroll
  for (int o = 1; o < 64; o <<= 1) {
    int up = __shfl_up(v, o);
    if (t >= o) v += up;
  }
  if (t < NB) bsumoff[p * 64 + t] = v - orig;
  if (t == 0) off[(size_t)p * (NN + 1) + NN] = EE;
}

__global__ void scan3_kernel(int* __restrict__ off, const int* __restrict__ bsumoff, int N) {
  int p = blockIdx.y, b = blockIdx.x;
  int add = bsumoff[p * 64 + b];
  #pragma unroll
  for (int j = 0; j < 4; j++) {
    int i = b * 1024 + j * 256 + (int)threadIdx.x;
    if (i < N) off[(size_t)p * (NN + 1) + i] += add;
  }
}

__global__ void fill_kernel(const int* __restrict__ src, const int* __restrict__ dst,
                            const int* __restrict__ off, int* __restrict__ cur,
                            int* __restrict__ csr, int PE, int E) {
  int t = blockIdx.x * 256 + threadIdx.x;
  if (t >= PE) return;
  int p = t / E;
  int d = dst[t];
  int slot = off[(size_t)p * (NN + 1) + d] + atomicAdd(&cur[p * NN + d], 1);
  csr[(size_t)p * E + slot] = src[t];
}

// ---------------------------------------------------------------------------
// Aggregation: one wave per dst node, SINGLE pass: out = (sum w*hp)/(sum w)
__global__ __launch_bounds__(256) void agg_kernel(
    const unsigned short* __restrict__ hp_b, const float* __restrict__ el,
    const float* __restrict__ er, const int* __restrict__ csr,
    const int* __restrict__ off, const float* __restrict__ bias,
    unsigned short* __restrict__ emb_b, int N) {
  int n = blockIdx.x * 4 + (threadIdx.x >> 6);
  if (n >= N) return;
  int lane = threadIdx.x & 63;
  int h = lane >> 3;
  int e0 = off[n], e1 = off[n + 1];
  float erh = er[n * NH + h];
  float den = 0.f, a0 = 0.f, a1 = 0.f, a2 = 0.f, a3 = 0.f;
  for (int e = e0; e < e1; e++) {
    int s = csr[e];
    float x = el[s * NH + h] + erh;
    x = (x > 0.f) ? x : 0.2f * x;
    float w = expf(x);
    den += w;
    ushort4 hv = *(const ushort4*)(hp_b + (size_t)s * HF + lane * 4);
    a0 += w * b2f(hv.x); a1 += w * b2f(hv.y);
    a2 += w * b2f(hv.z); a3 += w * b2f(hv.w);
  }
  float inv = (den > 0.f) ? 1.f / den : 0.f;
  float4 bv = *(const float4*)(bias + lane * 4);
  float o0 = a0 * inv + bv.x, o1 = a1 * inv + bv.y;
  float o2 = a2 * inv + bv.z, o3 = a3 * inv + bv.w;
  o0 = (o0 > 0.f) ? o0 : expf(o0) - 1.f;
  o1 = (o1 > 0.f) ? o1 : expf(o1) - 1.f;
  o2 = (o2 > 0.f) ? o2 : expf(o2) - 1.f;
  o3 = (o3 > 0.f) ? o3 : expf(o3) - 1.f;
  ushort4 ov;
  ov.x = f2b(o0); ov.y = f2b(o1); ov.z = f2b(o2); ov.w = f2b(o3);
  *(ushort4*)(emb_b + (size_t)n * HF + lane * 4) = ov;
}

// ---------------------------------------------------------------------------
// Pooling from bf16 emb: LDS 2-stage segment sum, 64-feat slice per block-x
__global__ __launch_bounds__(256) void pool_kernel(
    const unsigned short* __restrict__ emb, const int* __restrict__ gid,
    float* __restrict__ pool, int N) {
  __shared__ float acc[BG * 64];
  int f0 = blockIdx.x * 64;
  int lane = threadIdx.x & 63, grp = threadIdx.x >> 6;
  for (int i = threadIdx.x; i < BG * 64; i += 256) acc[i] = 0.f;
  __syncthreads();
  int nb = (int)gridDim.y;
  int chunk = (N + nb - 1) / nb;
  int start = blockIdx.y * chunk;
  int end = min(start + chunk, N);
  int glen = (end - start + 3) >> 2;
  int gstart = start + grp * glen;
  int gend = min(gstart + glen, end);
  for (int n = gstart; n < gend; n++) {
    int g = gid[n];
    float v = b2f(emb[(size_t)n * HF + f0 + lane]);
    atomicAdd(&acc[g * 64 + lane], v);
  }
  __syncthreads();
  for (int i = threadIdx.x; i < BG * 64; i += 256) {
    float v = acc[i];
    if (v != 0.f) {
      int g = i >> 6, f = i & 63;
      atomicAdd(&pool[g * HF + f0 + f], v);
    }
  }
}

// ---------------------------------------------------------------------------
__global__ __launch_bounds__(256) void final_kernel(
    const float* __restrict__ pool, const float* __restrict__ wsum,
    const float* __restrict__ cnt, const float* __restrict__ clsW,
    const float* __restrict__ clsb, float* __restrict__ out, int N) {
  int b = blockIdx.x;
  int f = threadIdx.x;
  float wm[PM];
  float mx = -1e30f;
  #pragma unroll
  for (int p = 0; p < PM; p++) { wm[p] = wsum[p] / (float)N; mx = fmaxf(mx, wm[p]); }
  float es = 0.f, e[PM];
  #pragma unroll
  for (int p = 0; p < PM; p++) { e[p] = expf(wm[p] - mx); es += e[p]; }
  float c = fmaxf(cnt[b], 1.f);
  float v = 0.f;
  #pragma unroll
  for (int p = 0; p < PM; p++)
    v += (e[p] / es) * pool[((size_t)p * BG + b) * HF + f];
  v /= c;
  out[256 + (size_t)b * HF + f] = v;
  __shared__ float sm[256];
  sm[f] = v * clsW[f * 2 + 0];
  __syncthreads();
  for (int st = 128; st > 0; st >>= 1) {
    if (f < st) sm[f] += sm[f + st];
    __syncthreads();
  }
  float l0 = sm[0];
  __syncthreads();
  sm[f] = v * clsW[f * 2 + 1];
  __syncthreads();
  for (int st = 128; st > 0; st >>= 1) {
    if (f < st) sm[f] += sm[f + st];
    __syncthreads();
  }
  if (f == 0) {
    out[b * 2 + 0] = l0 + clsb[0];
    out[b * 2 + 1] = sm[0] + clsb[1];
  }
}

// ---------------------------------------------------------------------------
extern "C" void kernel_launch(void* const* d_in, const int* in_sizes, int n_in,
                              void* d_out, int out_size, void* d_ws, size_t ws_size,
                              hipStream_t stream) {
  const float* h      = (const float*)d_in[0];
  const float* Wg     = (const float*)d_in[1];
  const float* attn_l = (const float*)d_in[2];
  const float* attn_r = (const float*)d_in[3];
  const float* gatb   = (const float*)d_in[4];
  const float* semW1  = (const float*)d_in[5];
  const float* semb1  = (const float*)d_in[6];
  const float* semW2  = (const float*)d_in[7];
  const float* clsW   = (const float*)d_in[8];
  const float* clsb   = (const float*)d_in[9];
  const int*   src    = (const int*)d_in[10];
  const int*   dst    = (const int*)d_in[11];
  const int*   gid    = (const int*)d_in[12];
  float* out = (float*)d_out;

  char* ws = (char*)d_ws;
  size_t o = 0;
  auto alloc = [&](size_t bytes) { size_t r = o; o += (bytes + 255) & ~(size_t)255; return r; };
  unsigned short* h_b   = (unsigned short*)(ws + alloc((size_t)NN * INF_ * 2));
  unsigned short* hp_b  = (unsigned short*)(ws + alloc((size_t)NN * HF * 2));
  unsigned short* emb_b = (unsigned short*)(ws + alloc((size_t)NN * HF * 2));
  unsigned short* Wb_t  = (unsigned short*)(ws + alloc((size_t)PM * HF * INF_ * 2));
  unsigned short* W1_t  = (unsigned short*)(ws + alloc((size_t)HS * HF * 2));
  float* wl   = (float*)(ws + alloc((size_t)PM * INF_ * NH * 4));
  float* wr   = (float*)(ws + alloc((size_t)PM * INF_ * NH * 4));
  float* el   = (float*)(ws + alloc((size_t)NN * NH * 4));
  float* er   = (float*)(ws + alloc((size_t)NN * NH * 4));
  int*   deg  = (int*)(ws + alloc((size_t)PM * NN * 4));
  int*   off  = (int*)(ws + alloc((size_t)PM * (NN + 1) * 4));
  int*   cur  = (int*)(ws + alloc((size_t)PM * NN * 4));
  int*   csr  = (int*)(ws + alloc((size_t)PM * EE * 4));
  int*   bsum    = (int*)(ws + alloc(PM * 64 * 4));
  int*   bsumoff = (int*)(ws + alloc(PM * 64 * 4));
  float* pool = (float*)(ws + alloc((size_t)PM * BG * HF * 4));
  float* wsum = (float*)(ws + alloc(PM * 4));
  float* cnt  = (float*)(ws + alloc(BG * 4));

  hipMemsetAsync(deg, 0, (size_t)PM * NN * 4, stream);
  hipMemsetAsync(cur, 0, (size_t)PM * NN * 4, stream);
  hipMemsetAsync(pool, 0, (size_t)PM * BG * HF * 4, stream);
  hipMemsetAsync(wsum, 0, PM * 4, stream);
  hipMemsetAsync(cnt, 0, BG * 4, stream);

  const int PE = PM * EE;
  const int NB = (NN + 1023) / 1024;   // 49

  f2b_kernel<<<((NN * INF_ / 4) + 255) / 256, 256, 0, stream>>>(h, h_b, NN * INF_ / 4);
  twg_kernel<<<(PM * HF * INF_ + 255) / 256, 256, 0, stream>>>(Wg, Wb_t);
  tw1_kernel<<<(HF * HS + 255) / 256, 256, 0, stream>>>(semW1, W1_t);
  fold_kernel<<<(PM * INF_ * NH + 255) / 256, 256, 0, stream>>>(Wg, attn_l, attn_r, wl, wr);

  count_kernel<<<(PE + 255) / 256, 256, 0, stream>>>(dst, deg, PE, EE);
  cntg_kernel<<<(NN + 255) / 256, 256, 0, stream>>>(gid, cnt, NN);
  scan1_kernel<<<dim3(NB, PM), 1024, 0, stream>>>(deg, off, bsum, NN);
  scan2_kernel<<<PM, 64, 0, stream>>>(bsum, bsumoff, off, NB);
  scan3_kernel<<<dim3(NB, PM), 256, 0, stream>>>(off, bsumoff, NN);
  fill_kernel<<<(PE + 255) / 256, 256, 0, stream>>>(src, dst, off, cur, csr, PE, EE);

  for (int p = 0; p < PM; p++) {
    gemm1_kernel<<<dim3((NN + 63) / 64, 2), 256, 0, stream>>>(
        h_b, Wb_t + (size_t)p * HF * INF_, hp_b, NN);
    elr_kernel<<<(NN + 255) / 256, 256, 0, stream>>>(
        h, wl + (size_t)p * INF_ * NH, wr + (size_t)p * INF_ * NH, el, er, NN);
    agg_kernel<<<(NN + 3) / 4, 256, 0, stream>>>(
        hp_b, el, er, csr + (size_t)p * EE, off + (size_t)p * (NN + 1),
        gatb + (size_t)p * HF, emb_b, NN);
    gemm2_kernel<<<(NN + 63) / 64, 256, 0, stream>>>(
        emb_b, W1_t, semb1, semW2, wsum + p, NN);
    pool_kernel<<<dim3(4, 64), 256, 0, stream>>>(emb_b, gid, pool + (size_t)p * BG * HF, NN);
  }

  final_kernel<<<BG, 256, 0, stream>>>(pool, wsum, cnt, clsW, clsb, out, NN);
}